// Round 2
// baseline (1322.271 us; speedup 1.0000x reference)
//
#include <hip/hip_runtime.h>
#include <math.h>

#define N_NODES 50000
#define N_EDGES 400000
#define N_TRAIN 50000
#define IN_DIM  128
#define HIDDEN  512

// ---------------- graph preprocessing ----------------

__global__ void count_dst_kernel(const int* __restrict__ dst, int* __restrict__ cnt) {
    int i = blockIdx.x * blockDim.x + threadIdx.x;
    if (i < N_EDGES) atomicAdd(&cnt[dst[i]], 1);
}

__global__ void dis_kernel(const int* __restrict__ cnt, float* __restrict__ dis) {
    int v = blockIdx.x * blockDim.x + threadIdx.x;
    if (v < N_NODES) dis[v] = rsqrtf(1.0f + (float)cnt[v]);  // +1 self-loop
}

// single-block exclusive scan of cnt -> off (N_NODES+1 entries)
__global__ void scan_kernel(const int* __restrict__ cnt, int* __restrict__ off) {
    __shared__ int part[1024];
    const int T = 1024;
    const int chunk = (N_NODES + T - 1) / T;  // 49
    int t = threadIdx.x;
    int s = t * chunk, e = min(s + chunk, N_NODES);
    int sum = 0;
    for (int i = s; i < e; i++) sum += cnt[i];
    part[t] = sum;
    __syncthreads();
    for (int o = 1; o < T; o <<= 1) {
        int v = (t >= o) ? part[t - o] : 0;
        __syncthreads();
        part[t] += v;
        __syncthreads();
    }
    int run = part[t] - sum;  // exclusive prefix
    for (int i = s; i < e; i++) { off[i] = run; run += cnt[i]; }
    if (t == T - 1) off[N_NODES] = run;
}

__global__ void fill_csr_kernel(const int* __restrict__ src, const int* __restrict__ dst,
                                const int* __restrict__ off, int* __restrict__ cursor,
                                int* __restrict__ csr_src) {
    int i = blockIdx.x * blockDim.x + threadIdx.x;
    if (i < N_EDGES) {
        int d = dst[i];
        int p = atomicAdd(&cursor[d], 1);
        csr_src[off[d] + p] = src[i];
    }
}

// ---------------- aggregation: out = A_norm @ h ----------------
// D floats per node, float4 per thread.
template <int D>
__global__ void agg_kernel(const float* __restrict__ h, const float* __restrict__ dis,
                           const int* __restrict__ off, const int* __restrict__ csr_src,
                           float* __restrict__ out) {
    constexpr int TPN = D / 4;        // threads per node
    constexpr int NPB = 256 / TPN;    // nodes per block
    int node = blockIdx.x * NPB + threadIdx.x / TPN;
    if (node >= N_NODES) return;
    int t = threadIdx.x % TPN;
    float dv = dis[node];
    float4 a = ((const float4*)(h + (size_t)node * D))[t];
    float w0 = dv * dv;  // self-loop norm
    float4 acc = make_float4(a.x * w0, a.y * w0, a.z * w0, a.w * w0);
    int s0 = off[node], s1 = off[node + 1];
    for (int k = s0; k < s1; k++) {
        int s = csr_src[k];
        float w = dis[s] * dv;
        float4 b = ((const float4*)(h + (size_t)s * D))[t];
        acc.x = fmaf(w, b.x, acc.x);
        acc.y = fmaf(w, b.y, acc.y);
        acc.z = fmaf(w, b.z, acc.z);
        acc.w = fmaf(w, b.w, acc.w);
    }
    ((float4*)(out + (size_t)node * D))[t] = acc;
}

// ---------------- f32 GEMM + bias + tanh ----------------
// C[M][512] = tanh(A[M][K] @ B[K][512] + bias)
__global__ __launch_bounds__(256) void gemm_bias_tanh_kernel(
    const float* __restrict__ A, const float* __restrict__ B,
    const float* __restrict__ bias, float* __restrict__ C,
    int M, int K) {
    const int N = HIDDEN;
    __shared__ float As[16][68];  // transposed A tile, padded
    __shared__ float Bs[16][68];
    int tid = threadIdx.x;
    int i0 = blockIdx.y * 64, j0 = blockIdx.x * 64;
    int row4 = (tid / 16) * 4;   // 0..60
    int col4 = (tid % 16) * 4;
    int ac = tid % 16, ar0 = (tid / 16) * 4;   // A-load: col, base row
    int bc = tid % 64, br0 = tid / 64;         // B-load: col, base row
    float acc[4][4] = {};
    for (int k0 = 0; k0 < K; k0 += 16) {
        #pragma unroll
        for (int i = 0; i < 4; i++) {
            int gi = i0 + ar0 + i;
            float v = (gi < M) ? A[(size_t)gi * K + k0 + ac] : 0.0f;
            As[ac][ar0 + i] = v;
        }
        #pragma unroll
        for (int i = 0; i < 4; i++) {
            int r = br0 + i * 4;
            Bs[r][bc] = B[(size_t)(k0 + r) * N + j0 + bc];
        }
        __syncthreads();
        #pragma unroll
        for (int kk = 0; kk < 16; kk++) {
            float4 a4 = *(const float4*)&As[kk][row4];
            float4 b4 = *(const float4*)&Bs[kk][col4];
            float av[4] = {a4.x, a4.y, a4.z, a4.w};
            float bv[4] = {b4.x, b4.y, b4.z, b4.w};
            #pragma unroll
            for (int x = 0; x < 4; x++)
                #pragma unroll
                for (int y = 0; y < 4; y++)
                    acc[x][y] = fmaf(av[x], bv[y], acc[x][y]);
        }
        __syncthreads();
    }
    #pragma unroll
    for (int x = 0; x < 4; x++) {
        int gi = i0 + row4 + x;
        if (gi >= M) continue;
        float4 o;
        o.x = tanhf(acc[x][0] + bias[j0 + col4 + 0]);
        o.y = tanhf(acc[x][1] + bias[j0 + col4 + 1]);
        o.z = tanhf(acc[x][2] + bias[j0 + col4 + 2]);
        o.w = tanhf(acc[x][3] + bias[j0 + col4 + 3]);
        *(float4*)&C[(size_t)gi * N + j0 + col4] = o;
    }
}

// ---------------- final edge scoring ----------------
// out[e] = sum_d h[a][d]*h[b][d]*w[d] + fc2_b
__global__ void edge_score_kernel(const float* __restrict__ h,
                                  const int* __restrict__ src, const int* __restrict__ dst,
                                  const int* __restrict__ te, const float* __restrict__ w,
                                  const float* __restrict__ fc2b, float* __restrict__ out) {
    int wid = threadIdx.x / 64;
    int lane = threadIdx.x % 64;
    int e = blockIdx.x * 4 + wid;
    if (e >= N_TRAIN) return;
    int id = te[e];
    int a = src[id], b = dst[id];
    const float4* ha = (const float4*)(h + (size_t)a * HIDDEN);
    const float4* hb = (const float4*)(h + (size_t)b * HIDDEN);
    const float4* wf = (const float4*)w;
    float acc = 0.f;
    #pragma unroll
    for (int i = 0; i < 2; i++) {
        int idx = lane * 2 + i;  // float4 index 0..127
        float4 x = ha[idx], y = hb[idx], z = wf[idx];
        acc += x.x * y.x * z.x + x.y * y.y * z.y + x.z * y.z * z.z + x.w * y.w * z.w;
    }
    #pragma unroll
    for (int o = 32; o > 0; o >>= 1) acc += __shfl_down(acc, o);
    if (lane == 0) out[e] = acc + fc2b[0];
}

// ---------------- launch ----------------

extern "C" void kernel_launch(void* const* d_in, const int* in_sizes, int n_in,
                              void* d_out, int out_size, void* d_ws, size_t ws_size,
                              hipStream_t stream) {
    const float* x    = (const float*)d_in[0];
    const int*   eidx = (const int*)d_in[1];
    const int*   te   = (const int*)d_in[2];
    const float* W1   = (const float*)d_in[3];
    const float* b1   = (const float*)d_in[4];
    const float* W2   = (const float*)d_in[5];
    const float* b2   = (const float*)d_in[6];
    const float* W3   = (const float*)d_in[7];
    const float* b3   = (const float*)d_in[8];
    const float* fc2W = (const float*)d_in[9];
    const float* fc2b = (const float*)d_in[10];
    const int* srcp = eidx;
    const int* dstp = eidx + N_EDGES;

    char* ws = (char*)d_ws;
    size_t used = 0;
    auto alloc = [&](size_t bytes) {
        void* p = ws + used;
        used += (bytes + 255) / 256 * 256;
        return p;
    };
    int*   cnt     = (int*)alloc((size_t)N_NODES * 4);
    int*   off     = (int*)alloc((size_t)(N_NODES + 1) * 4);
    int*   cursor  = (int*)alloc((size_t)N_NODES * 4);
    int*   csr_src = (int*)alloc((size_t)N_EDGES * 4);
    float* dis     = (float*)alloc((size_t)N_NODES * 4);
    float* P       = (float*)alloc((size_t)N_NODES * HIDDEN * 4);  // ping
    float* Q       = (float*)alloc((size_t)N_NODES * HIDDEN * 4);  // pong

    if (used > ws_size) return;  // workspace too small: fail cleanly, no OOB write

    hipMemsetAsync(cnt, 0, (size_t)N_NODES * 4, stream);
    hipMemsetAsync(cursor, 0, (size_t)N_NODES * 4, stream);

    count_dst_kernel<<<(N_EDGES + 255) / 256, 256, 0, stream>>>(dstp, cnt);
    dis_kernel<<<(N_NODES + 255) / 256, 256, 0, stream>>>(cnt, dis);
    scan_kernel<<<1, 1024, 0, stream>>>(cnt, off);
    fill_csr_kernel<<<(N_EDGES + 255) / 256, 256, 0, stream>>>(srcp, dstp, off, cursor, csr_src);

    dim3 gemm_grid(HIDDEN / 64, (N_NODES + 63) / 64);

    // layer 1: P = agg(x) (128-wide);  Q = tanh(P @ W1 + b1)
    agg_kernel<IN_DIM><<<(N_NODES + 7) / 8, 256, 0, stream>>>(x, dis, off, csr_src, P);
    gemm_bias_tanh_kernel<<<gemm_grid, 256, 0, stream>>>(P, W1, b1, Q, N_NODES, IN_DIM);
    // layer 2: P = agg(Q);  Q = tanh(P @ W2 + b2)
    agg_kernel<HIDDEN><<<(N_NODES + 1) / 2, 256, 0, stream>>>(Q, dis, off, csr_src, P);
    gemm_bias_tanh_kernel<<<gemm_grid, 256, 0, stream>>>(P, W2, b2, Q, N_NODES, HIDDEN);
    // layer 3: P = agg(Q);  Q = tanh(P @ W3 + b3)
    agg_kernel<HIDDEN><<<(N_NODES + 1) / 2, 256, 0, stream>>>(Q, dis, off, csr_src, P);
    gemm_bias_tanh_kernel<<<gemm_grid, 256, 0, stream>>>(P, W3, b3, Q, N_NODES, HIDDEN);
    // final scoring
    edge_score_kernel<<<(N_TRAIN + 3) / 4, 256, 0, stream>>>(Q, srcp, dstp, te, fc2W, fc2b,
                                                             (float*)d_out);
}

// Round 3
// 940.018 us; speedup vs baseline: 1.4066x; 1.4066x over previous
//
#include <hip/hip_runtime.h>
#include <math.h>

#define N_NODES 50000
#define N_EDGES 400000
#define N_TRAIN 50000
#define IN_DIM  128
#define HIDDEN  512
#define M_PAD   50048   // 391 * 128

typedef __attribute__((ext_vector_type(8))) short bf16x8;
typedef __attribute__((ext_vector_type(4))) float f32x4;

__device__ inline unsigned short f2bf(float f) {
    unsigned u = __float_as_uint(f);
    u += 0x7FFF + ((u >> 16) & 1);   // RNE
    return (unsigned short)(u >> 16);
}
__device__ inline float bf2f(unsigned short h) {
    return __uint_as_float(((unsigned)h) << 16);
}

// ---------------- graph preprocessing ----------------

__global__ void count_dst_kernel(const int* __restrict__ dst, int* __restrict__ cnt) {
    int i = blockIdx.x * blockDim.x + threadIdx.x;
    if (i < N_EDGES) atomicAdd(&cnt[dst[i]], 1);
}

__global__ void dis_kernel(const int* __restrict__ cnt, float* __restrict__ dis) {
    int v = blockIdx.x * blockDim.x + threadIdx.x;
    if (v < N_NODES) dis[v] = rsqrtf(1.0f + (float)cnt[v]);  // +1 self-loop
}

__global__ void scan_kernel(const int* __restrict__ cnt, int* __restrict__ off) {
    __shared__ int part[1024];
    const int T = 1024;
    const int chunk = (N_NODES + T - 1) / T;
    int t = threadIdx.x;
    int s = t * chunk, e = min(s + chunk, N_NODES);
    int sum = 0;
    for (int i = s; i < e; i++) sum += cnt[i];
    part[t] = sum;
    __syncthreads();
    for (int o = 1; o < T; o <<= 1) {
        int v = (t >= o) ? part[t - o] : 0;
        __syncthreads();
        part[t] += v;
        __syncthreads();
    }
    int run = part[t] - sum;
    for (int i = s; i < e; i++) { off[i] = run; run += cnt[i]; }
    if (t == T - 1) off[N_NODES] = run;
}

__global__ void fill_csr_kernel(const int* __restrict__ src, const int* __restrict__ dst,
                                const int* __restrict__ off, int* __restrict__ cursor,
                                int* __restrict__ csr_src) {
    int i = blockIdx.x * blockDim.x + threadIdx.x;
    if (i < N_EDGES) {
        int d = dst[i];
        int p = atomicAdd(&cursor[d], 1);
        csr_src[off[d] + p] = src[i];
    }
}

// ---------------- weight conversion: W[K][512] -> Bt[512][3K] = [hi; lo; hi]^T ----------------
__global__ void convw_kernel(const float* __restrict__ W, unsigned short* __restrict__ Bt, int K) {
    int idx = blockIdx.x * blockDim.x + threadIdx.x;
    if (idx >= K * HIDDEN) return;
    int k = idx / HIDDEN, n = idx % HIDDEN;
    float w = W[(size_t)k * HIDDEN + n];
    unsigned short hi = f2bf(w);
    unsigned short lo = f2bf(w - bf2f(hi));
    size_t base = (size_t)n * 3 * K;
    Bt[base + k]         = hi;
    Bt[base + K + k]     = lo;
    Bt[base + 2 * K + k] = hi;
}

// ---------------- layer-1 aggregation: f32 x (D=128) -> hi/lo pair (stride 128) ------------
__global__ void agg1_kernel(const float* __restrict__ x, const float* __restrict__ dis,
                            const int* __restrict__ off, const int* __restrict__ csr_src,
                            unsigned short* __restrict__ Ahi, unsigned short* __restrict__ Alo) {
    const int TPN = 32;   // 128/4
    int node = blockIdx.x * 8 + threadIdx.x / TPN;
    if (node >= N_NODES) return;
    int t = threadIdx.x % TPN;
    float dv = dis[node];
    float w0 = dv * dv;
    float4 a = ((const float4*)(x + (size_t)node * IN_DIM))[t];
    float4 acc = make_float4(a.x * w0, a.y * w0, a.z * w0, a.w * w0);
    int s0 = off[node], s1 = off[node + 1];
    for (int k = s0; k < s1; k++) {
        int s = csr_src[k];
        float w = dis[s] * dv;
        float4 b = ((const float4*)(x + (size_t)s * IN_DIM))[t];
        acc.x = fmaf(w, b.x, acc.x);
        acc.y = fmaf(w, b.y, acc.y);
        acc.z = fmaf(w, b.z, acc.z);
        acc.w = fmaf(w, b.w, acc.w);
    }
    ushort4 oh, ol;
    oh.x = f2bf(acc.x); ol.x = f2bf(acc.x - bf2f(oh.x));
    oh.y = f2bf(acc.y); ol.y = f2bf(acc.y - bf2f(oh.y));
    oh.z = f2bf(acc.z); ol.z = f2bf(acc.z - bf2f(oh.z));
    oh.w = f2bf(acc.w); ol.w = f2bf(acc.w - bf2f(oh.w));
    size_t o = (size_t)node * IN_DIM + t * 4;
    *(ushort4*)&Ahi[o] = oh;
    *(ushort4*)&Alo[o] = ol;
}

// ---------------- pair aggregation: hi/lo (D=512) -> hi/lo (stride 512) ----------------
__global__ void agg_pair_kernel(const unsigned short* __restrict__ Hhi,
                                const unsigned short* __restrict__ Hlo,
                                const float* __restrict__ dis,
                                const int* __restrict__ off, const int* __restrict__ csr_src,
                                unsigned short* __restrict__ Ahi, unsigned short* __restrict__ Alo) {
    const int TPN = 128;  // 512/4
    int node = blockIdx.x * 2 + threadIdx.x / TPN;
    if (node >= N_NODES) return;
    int t = threadIdx.x % TPN;
    float dv = dis[node];
    float w0 = dv * dv;
    size_t base = (size_t)node * HIDDEN + t * 4;
    ushort4 h4 = *(const ushort4*)&Hhi[base];
    ushort4 l4 = *(const ushort4*)&Hlo[base];
    float4 acc;
    acc.x = w0 * (bf2f(h4.x) + bf2f(l4.x));
    acc.y = w0 * (bf2f(h4.y) + bf2f(l4.y));
    acc.z = w0 * (bf2f(h4.z) + bf2f(l4.z));
    acc.w = w0 * (bf2f(h4.w) + bf2f(l4.w));
    int s0 = off[node], s1 = off[node + 1];
    for (int k = s0; k < s1; k++) {
        int s = csr_src[k];
        float w = dis[s] * dv;
        size_t sb = (size_t)s * HIDDEN + t * 4;
        ushort4 hh = *(const ushort4*)&Hhi[sb];
        ushort4 ll = *(const ushort4*)&Hlo[sb];
        acc.x = fmaf(w, bf2f(hh.x) + bf2f(ll.x), acc.x);
        acc.y = fmaf(w, bf2f(hh.y) + bf2f(ll.y), acc.y);
        acc.z = fmaf(w, bf2f(hh.z) + bf2f(ll.z), acc.z);
        acc.w = fmaf(w, bf2f(hh.w) + bf2f(ll.w), acc.w);
    }
    ushort4 oh, ol;
    oh.x = f2bf(acc.x); ol.x = f2bf(acc.x - bf2f(oh.x));
    oh.y = f2bf(acc.y); ol.y = f2bf(acc.y - bf2f(oh.y));
    oh.z = f2bf(acc.z); ol.z = f2bf(acc.z - bf2f(oh.z));
    oh.w = f2bf(acc.w); ol.w = f2bf(acc.w - bf2f(oh.w));
    *(ushort4*)&Ahi[base] = oh;
    *(ushort4*)&Alo[base] = ol;
}

// ---------------- MFMA split-bf16 GEMM + bias + tanh + re-split ----------------
// C[M][512] = tanh(A' @ B' + bias), A' = [A_hi | A_hi | A_lo] (M x 3Kb, logical),
// Bt = [512][3Kb] (B'^T: rows n, cols k' = [hi; lo; hi]).
// Tile 128x128, 4 waves (2x2 of 64x64), BK=64, 16x16x32 bf16 MFMA.
__global__ __launch_bounds__(256) void gemm_mfma_kernel(
    const unsigned short* __restrict__ Ahi, const unsigned short* __restrict__ Alo,
    const unsigned short* __restrict__ Bt, const float* __restrict__ bias,
    unsigned short* __restrict__ Ohi, unsigned short* __restrict__ Olo,
    int M, int Kb) {
    __shared__ unsigned short As[128 * 64];  // [row][k] row-major
    __shared__ unsigned short Bs[128 * 64];  // [col][k] (B^T tile)
    const int Kp = 3 * Kb;
    int tid = threadIdx.x;
    int lane = tid & 63, w = tid >> 6;
    int wr = w >> 1, wc = w & 1;
    int i0 = blockIdx.y * 128, j0 = blockIdx.x * 128;
    int l15 = lane & 15, l4 = lane >> 4;

    f32x4 acc[4][4];
    #pragma unroll
    for (int m = 0; m < 4; m++)
        #pragma unroll
        for (int n = 0; n < 4; n++)
            acc[m][n] = (f32x4){0.f, 0.f, 0.f, 0.f};

    for (int k0 = 0; k0 < Kp; k0 += 64) {
        int part = (k0 >= 2 * Kb) ? 2 : (k0 >= Kb ? 1 : 0);
        int koff = k0 - part * Kb;
        const unsigned short* Asrc = (part == 2) ? Alo : Ahi;
        #pragma unroll
        for (int i = 0; i < 4; i++) {
            int l = i * 256 + w * 64 + lane;
            int row = l >> 3, c8 = l & 7;
            const unsigned short* gp = Asrc + (size_t)(i0 + row) * Kb + koff + c8 * 8;
            unsigned short* lp = &As[(i * 256 + w * 64) * 8];  // wave-uniform base
            __builtin_amdgcn_global_load_lds(
                (const __attribute__((address_space(1))) void*)gp,
                (__attribute__((address_space(3))) void*)lp, 16, 0, 0);
        }
        #pragma unroll
        for (int i = 0; i < 4; i++) {
            int l = i * 256 + w * 64 + lane;
            int row = l >> 3, c8 = l & 7;
            const unsigned short* gp = Bt + (size_t)(j0 + row) * Kp + k0 + c8 * 8;
            unsigned short* lp = &Bs[(i * 256 + w * 64) * 8];
            __builtin_amdgcn_global_load_lds(
                (const __attribute__((address_space(1))) void*)gp,
                (__attribute__((address_space(3))) void*)lp, 16, 0, 0);
        }
        __syncthreads();   // drains vmcnt -> tiles resident

        bf16x8 af[4][2], bfr[4][2];
        #pragma unroll
        for (int m = 0; m < 4; m++)
            #pragma unroll
            for (int kk = 0; kk < 2; kk++)
                af[m][kk] = *(const bf16x8*)&As[(wr * 64 + m * 16 + l15) * 64 + kk * 32 + l4 * 8];
        #pragma unroll
        for (int n = 0; n < 4; n++)
            #pragma unroll
            for (int kk = 0; kk < 2; kk++)
                bfr[n][kk] = *(const bf16x8*)&Bs[(wc * 64 + n * 16 + l15) * 64 + kk * 32 + l4 * 8];
        #pragma unroll
        for (int m = 0; m < 4; m++)
            #pragma unroll
            for (int n = 0; n < 4; n++)
                #pragma unroll
                for (int kk = 0; kk < 2; kk++)
                    acc[m][n] = __builtin_amdgcn_mfma_f32_16x16x32_bf16(
                        af[m][kk], bfr[n][kk], acc[m][n], 0, 0, 0);
        __syncthreads();   // protect LDS before next stage
    }

    #pragma unroll
    for (int m = 0; m < 4; m++) {
        #pragma unroll
        for (int n = 0; n < 4; n++) {
            int col = j0 + wc * 64 + n * 16 + l15;
            float bc = bias[col];
            #pragma unroll
            for (int r = 0; r < 4; r++) {
                int row = i0 + wr * 64 + m * 16 + l4 * 4 + r;
                if (row < M) {
                    float t = tanhf(acc[m][n][r] + bc);
                    unsigned short hi = f2bf(t);
                    unsigned short lo = f2bf(t - bf2f(hi));
                    size_t o = (size_t)row * HIDDEN + col;
                    Ohi[o] = hi;
                    Olo[o] = lo;
                }
            }
        }
    }
}

// ---------------- final edge scoring (pair input) ----------------
__global__ void edge_score_kernel(const unsigned short* __restrict__ Hhi,
                                  const unsigned short* __restrict__ Hlo,
                                  const int* __restrict__ src, const int* __restrict__ dst,
                                  const int* __restrict__ te, const float* __restrict__ wgt,
                                  const float* __restrict__ fc2b, float* __restrict__ out) {
    int wid = threadIdx.x / 64;
    int lane = threadIdx.x % 64;
    int e = blockIdx.x * 4 + wid;
    if (e >= N_TRAIN) return;
    int id = te[e];
    int a = src[id], b = dst[id];
    size_t ba = (size_t)a * HIDDEN + lane * 8;
    size_t bb = (size_t)b * HIDDEN + lane * 8;
    float acc = 0.f;
    #pragma unroll
    for (int half = 0; half < 2; half++) {
        ushort4 ah = *(const ushort4*)&Hhi[ba + half * 4];
        ushort4 al = *(const ushort4*)&Hlo[ba + half * 4];
        ushort4 bh = *(const ushort4*)&Hhi[bb + half * 4];
        ushort4 bl = *(const ushort4*)&Hlo[bb + half * 4];
        float4 wv = *(const float4*)&wgt[lane * 8 + half * 4];
        acc += (bf2f(ah.x) + bf2f(al.x)) * (bf2f(bh.x) + bf2f(bl.x)) * wv.x;
        acc += (bf2f(ah.y) + bf2f(al.y)) * (bf2f(bh.y) + bf2f(bl.y)) * wv.y;
        acc += (bf2f(ah.z) + bf2f(al.z)) * (bf2f(bh.z) + bf2f(bl.z)) * wv.z;
        acc += (bf2f(ah.w) + bf2f(al.w)) * (bf2f(bh.w) + bf2f(bl.w)) * wv.w;
    }
    #pragma unroll
    for (int o = 32; o > 0; o >>= 1) acc += __shfl_down(acc, o);
    if (lane == 0) out[e] = acc + fc2b[0];
}

// ---------------- launch ----------------

extern "C" void kernel_launch(void* const* d_in, const int* in_sizes, int n_in,
                              void* d_out, int out_size, void* d_ws, size_t ws_size,
                              hipStream_t stream) {
    const float* x    = (const float*)d_in[0];
    const int*   eidx = (const int*)d_in[1];
    const int*   te   = (const int*)d_in[2];
    const float* W1   = (const float*)d_in[3];
    const float* b1   = (const float*)d_in[4];
    const float* W2   = (const float*)d_in[5];
    const float* b2   = (const float*)d_in[6];
    const float* W3   = (const float*)d_in[7];
    const float* b3   = (const float*)d_in[8];
    const float* fc2W = (const float*)d_in[9];
    const float* fc2b = (const float*)d_in[10];
    const int* srcp = eidx;
    const int* dstp = eidx + N_EDGES;

    char* ws = (char*)d_ws;
    size_t used = 0;
    auto alloc = [&](size_t bytes) {
        void* p = ws + used;
        used += (bytes + 255) / 256 * 256;
        return p;
    };
    int*   cnt     = (int*)alloc((size_t)N_NODES * 4);
    int*   off     = (int*)alloc((size_t)(N_NODES + 1) * 4);
    int*   cursor  = (int*)alloc((size_t)N_NODES * 4);
    int*   csr_src = (int*)alloc((size_t)N_EDGES * 4);
    float* dis     = (float*)alloc((size_t)N_NODES * 4);
    unsigned short* Bt1 = (unsigned short*)alloc((size_t)HIDDEN * 3 * IN_DIM * 2);
    unsigned short* Bt2 = (unsigned short*)alloc((size_t)HIDDEN * 3 * HIDDEN * 2);
    unsigned short* Bt3 = (unsigned short*)alloc((size_t)HIDDEN * 3 * HIDDEN * 2);
    unsigned short* GAhi = (unsigned short*)alloc((size_t)M_PAD * HIDDEN * 2);
    unsigned short* GAlo = (unsigned short*)alloc((size_t)M_PAD * HIDDEN * 2);
    unsigned short* GBhi = (unsigned short*)alloc((size_t)M_PAD * HIDDEN * 2);
    unsigned short* GBlo = (unsigned short*)alloc((size_t)M_PAD * HIDDEN * 2);

    if (used > ws_size) return;  // fail cleanly rather than OOB

    hipMemsetAsync(cnt, 0, (size_t)N_NODES * 4, stream);
    hipMemsetAsync(cursor, 0, (size_t)N_NODES * 4, stream);

    count_dst_kernel<<<(N_EDGES + 255) / 256, 256, 0, stream>>>(dstp, cnt);
    dis_kernel<<<(N_NODES + 255) / 256, 256, 0, stream>>>(cnt, dis);
    scan_kernel<<<1, 1024, 0, stream>>>(cnt, off);
    fill_csr_kernel<<<(N_EDGES + 255) / 256, 256, 0, stream>>>(srcp, dstp, off, cursor, csr_src);

    convw_kernel<<<(IN_DIM * HIDDEN + 255) / 256, 256, 0, stream>>>(W1, Bt1, IN_DIM);
    convw_kernel<<<(HIDDEN * HIDDEN + 255) / 256, 256, 0, stream>>>(W2, Bt2, HIDDEN);
    convw_kernel<<<(HIDDEN * HIDDEN + 255) / 256, 256, 0, stream>>>(W3, Bt3, HIDDEN);

    dim3 gemm_grid(HIDDEN / 128, M_PAD / 128);

    // layer 1
    agg1_kernel<<<(N_NODES + 7) / 8, 256, 0, stream>>>(x, dis, off, csr_src, GAhi, GAlo);
    gemm_mfma_kernel<<<gemm_grid, 256, 0, stream>>>(GAhi, GAlo, Bt1, b1, GBhi, GBlo,
                                                    N_NODES, IN_DIM);
    // layer 2
    agg_pair_kernel<<<(N_NODES + 1) / 2, 256, 0, stream>>>(GBhi, GBlo, dis, off, csr_src,
                                                           GAhi, GAlo);
    gemm_mfma_kernel<<<gemm_grid, 256, 0, stream>>>(GAhi, GAlo, Bt2, b2, GBhi, GBlo,
                                                    N_NODES, HIDDEN);
    // layer 3
    agg_pair_kernel<<<(N_NODES + 1) / 2, 256, 0, stream>>>(GBhi, GBlo, dis, off, csr_src,
                                                           GAhi, GAlo);
    gemm_mfma_kernel<<<gemm_grid, 256, 0, stream>>>(GAhi, GAlo, Bt3, b3, GBhi, GBlo,
                                                    N_NODES, HIDDEN);
    // final scoring
    edge_score_kernel<<<(N_TRAIN + 3) / 4, 256, 0, stream>>>(GBhi, GBlo, srcp, dstp, te,
                                                             fc2W, fc2b, (float*)d_out);
}

// Round 4
// 847.631 us; speedup vs baseline: 1.5600x; 1.1090x over previous
//
#include <hip/hip_runtime.h>
#include <math.h>

#define N_NODES 50000
#define N_EDGES 400000
#define N_TRAIN 50000
#define IN_DIM  128
#define HIDDEN  512
#define M_PAD   50048   // 391 * 128

typedef __attribute__((ext_vector_type(8))) short bf16x8;
typedef __attribute__((ext_vector_type(4))) float f32x4;

__device__ inline unsigned short f2bf(float f) {
    unsigned u = __float_as_uint(f);
    u += 0x7FFF + ((u >> 16) & 1);   // RNE
    return (unsigned short)(u >> 16);
}
__device__ inline float bf2f(unsigned short h) {
    return __uint_as_float(((unsigned)h) << 16);
}

// ---------------- graph preprocessing ----------------

__global__ void count_dst_kernel(const int* __restrict__ dst, int* __restrict__ cnt) {
    int i = blockIdx.x * blockDim.x + threadIdx.x;
    if (i < N_EDGES) atomicAdd(&cnt[dst[i]], 1);
}

__global__ void dis_kernel(const int* __restrict__ cnt, float* __restrict__ dis) {
    int v = blockIdx.x * blockDim.x + threadIdx.x;
    if (v < N_NODES) dis[v] = rsqrtf(1.0f + (float)cnt[v]);  // +1 self-loop
}

__global__ void scan_kernel(const int* __restrict__ cnt, int* __restrict__ off) {
    __shared__ int part[1024];
    const int T = 1024;
    const int chunk = (N_NODES + T - 1) / T;
    int t = threadIdx.x;
    int s = t * chunk, e = min(s + chunk, N_NODES);
    int sum = 0;
    for (int i = s; i < e; i++) sum += cnt[i];
    part[t] = sum;
    __syncthreads();
    for (int o = 1; o < T; o <<= 1) {
        int v = (t >= o) ? part[t - o] : 0;
        __syncthreads();
        part[t] += v;
        __syncthreads();
    }
    int run = part[t] - sum;
    for (int i = s; i < e; i++) { off[i] = run; run += cnt[i]; }
    if (t == T - 1) off[N_NODES] = run;
}

__global__ void fill_csr_kernel(const int* __restrict__ src, const int* __restrict__ dst,
                                const int* __restrict__ off, int* __restrict__ cursor,
                                int* __restrict__ csr_src) {
    int i = blockIdx.x * blockDim.x + threadIdx.x;
    if (i < N_EDGES) {
        int d = dst[i];
        int p = atomicAdd(&cursor[d], 1);
        csr_src[off[d] + p] = src[i];
    }
}

// ---------------- weight conversion: W[K][512] -> Bt[512][3K] = [hi; lo; hi]^T ----------------
__global__ void convw_kernel(const float* __restrict__ W, unsigned short* __restrict__ Bt, int K) {
    int idx = blockIdx.x * blockDim.x + threadIdx.x;
    if (idx >= K * HIDDEN) return;
    int k = idx / HIDDEN, n = idx % HIDDEN;
    float w = W[(size_t)k * HIDDEN + n];
    unsigned short hi = f2bf(w);
    unsigned short lo = f2bf(w - bf2f(hi));
    size_t base = (size_t)n * 3 * K;
    Bt[base + k]         = hi;
    Bt[base + K + k]     = lo;
    Bt[base + 2 * K + k] = hi;
}

// ---------------- aggregation: f32 h (D wide) -> hi/lo split pair ----------------
// out(A_norm @ h) split into bf16 hi/lo, ready as GEMM A operand.
template <int D>
__global__ void agg_split_kernel(const float* __restrict__ h, const float* __restrict__ dis,
                                 const int* __restrict__ off, const int* __restrict__ csr_src,
                                 unsigned short* __restrict__ Ahi, unsigned short* __restrict__ Alo) {
    constexpr int TPN = D / 4;
    constexpr int NPB = 256 / TPN;
    int node = blockIdx.x * NPB + threadIdx.x / TPN;
    if (node >= N_NODES) return;
    int t = threadIdx.x % TPN;
    float dv = dis[node];
    float w0 = dv * dv;
    float4 a = ((const float4*)(h + (size_t)node * D))[t];
    float4 acc = make_float4(a.x * w0, a.y * w0, a.z * w0, a.w * w0);
    int s0 = off[node], s1 = off[node + 1];
    for (int k = s0; k < s1; k++) {
        int s = csr_src[k];
        float w = dis[s] * dv;
        float4 b = ((const float4*)(h + (size_t)s * D))[t];
        acc.x = fmaf(w, b.x, acc.x);
        acc.y = fmaf(w, b.y, acc.y);
        acc.z = fmaf(w, b.z, acc.z);
        acc.w = fmaf(w, b.w, acc.w);
    }
    ushort4 oh, ol;
    oh.x = f2bf(acc.x); ol.x = f2bf(acc.x - bf2f(oh.x));
    oh.y = f2bf(acc.y); ol.y = f2bf(acc.y - bf2f(oh.y));
    oh.z = f2bf(acc.z); ol.z = f2bf(acc.z - bf2f(oh.z));
    oh.w = f2bf(acc.w); ol.w = f2bf(acc.w - bf2f(oh.w));
    size_t o = (size_t)node * D + t * 4;
    *(ushort4*)&Ahi[o] = oh;
    *(ushort4*)&Alo[o] = ol;
}

// ---------------- MFMA split-bf16 GEMM + bias + tanh -> f32 ----------------
// C[M][512] = tanh(A' @ B' + bias), A' = [A_hi | A_hi | A_lo] (M x 3Kb, logical),
// Bt = [512][3Kb]. Tile 128x128, 4 waves (2x2 of 64x64), BK=64, 16x16x32 bf16 MFMA.
// LDS XOR-swizzle (T2, rule #21): linear LDS dest, inverse-swizzled GLOBAL src,
// swizzled ds_read -> 16-way bank conflict becomes ~2-way (free).
__global__ __launch_bounds__(256) void gemm_mfma_kernel(
    const unsigned short* __restrict__ Ahi, const unsigned short* __restrict__ Alo,
    const unsigned short* __restrict__ Bt, const float* __restrict__ bias,
    float* __restrict__ C, int M, int Kb) {
    __shared__ unsigned short As[128 * 64];  // [row][k], 128B rows, slot = 16B unit
    __shared__ unsigned short Bs[128 * 64];
    const int Kp = 3 * Kb;
    int tid = threadIdx.x;
    int lane = tid & 63, w = tid >> 6;
    int wr = w >> 1, wc = w & 1;

    // bijective XCD swizzle (m204): contiguous wgid chunk per XCD so the 4
    // column-tile siblings (same A panel) share one XCD's L2.
    int nwg = gridDim.x;                 // 1564
    int q = nwg >> 3, r = nwg & 7;
    int xcd = blockIdx.x & 7, pos = blockIdx.x >> 3;
    int wgid = (xcd < r ? xcd * (q + 1) : r * (q + 1) + (xcd - r) * q) + pos;
    int j0 = (wgid & 3) * 128;           // col tile (HIDDEN/128 = 4)
    int i0 = (wgid >> 2) * 128;          // row tile

    int l15 = lane & 15, l4 = lane >> 4;

    f32x4 acc[4][4];
    #pragma unroll
    for (int m = 0; m < 4; m++)
        #pragma unroll
        for (int n = 0; n < 4; n++)
            acc[m][n] = (f32x4){0.f, 0.f, 0.f, 0.f};

    for (int k0 = 0; k0 < Kp; k0 += 64) {
        int part = (k0 >= 2 * Kb) ? 2 : (k0 >= Kb ? 1 : 0);
        int koff = k0 - part * Kb;
        const unsigned short* Asrc = (part == 2) ? Alo : Ahi;
        #pragma unroll
        for (int i = 0; i < 4; i++) {
            int s = i * 256 + w * 64 + lane;      // 16B slot index 0..1023
            int row = s >> 3, c8 = s & 7;
            int c8s = c8 ^ (row & 7);             // pre-swizzled source column
            const unsigned short* gp = Asrc + (size_t)(i0 + row) * Kb + koff + c8s * 8;
            unsigned short* lp = &As[(i * 256 + w * 64) * 8];  // wave-uniform base
            __builtin_amdgcn_global_load_lds(
                (const __attribute__((address_space(1))) void*)gp,
                (__attribute__((address_space(3))) void*)lp, 16, 0, 0);
        }
        #pragma unroll
        for (int i = 0; i < 4; i++) {
            int s = i * 256 + w * 64 + lane;
            int row = s >> 3, c8 = s & 7;
            int c8s = c8 ^ (row & 7);
            const unsigned short* gp = Bt + (size_t)(j0 + row) * Kp + k0 + c8s * 8;
            unsigned short* lp = &Bs[(i * 256 + w * 64) * 8];
            __builtin_amdgcn_global_load_lds(
                (const __attribute__((address_space(1))) void*)gp,
                (__attribute__((address_space(3))) void*)lp, 16, 0, 0);
        }
        __syncthreads();   // drains vmcnt -> tiles resident

        bf16x8 af[4][2], bfr[4][2];
        #pragma unroll
        for (int m = 0; m < 4; m++) {
            int row = wr * 64 + m * 16 + l15;
            #pragma unroll
            for (int kk = 0; kk < 2; kk++) {
                int slot = (kk * 4 + l4) ^ (row & 7);
                af[m][kk] = *(const bf16x8*)&As[row * 64 + slot * 8];
            }
        }
        #pragma unroll
        for (int n = 0; n < 4; n++) {
            int row = wc * 64 + n * 16 + l15;
            #pragma unroll
            for (int kk = 0; kk < 2; kk++) {
                int slot = (kk * 4 + l4) ^ (row & 7);
                bfr[n][kk] = *(const bf16x8*)&Bs[row * 64 + slot * 8];
            }
        }
        #pragma unroll
        for (int m = 0; m < 4; m++)
            #pragma unroll
            for (int n = 0; n < 4; n++)
                #pragma unroll
                for (int kk = 0; kk < 2; kk++)
                    acc[m][n] = __builtin_amdgcn_mfma_f32_16x16x32_bf16(
                        af[m][kk], bfr[n][kk], acc[m][n], 0, 0, 0);
        __syncthreads();   // protect LDS before next stage
    }

    #pragma unroll
    for (int m = 0; m < 4; m++) {
        #pragma unroll
        for (int n = 0; n < 4; n++) {
            int col = j0 + wc * 64 + n * 16 + l15;
            float bc = bias[col];
            #pragma unroll
            for (int r = 0; r < 4; r++) {
                int row = i0 + wr * 64 + m * 16 + l4 * 4 + r;
                if (row < M)
                    C[(size_t)row * HIDDEN + col] = tanhf(acc[m][n][r] + bc);
            }
        }
    }
}

// ---------------- final edge scoring (f32 input) ----------------
__global__ void edge_score_kernel(const float* __restrict__ h,
                                  const int* __restrict__ src, const int* __restrict__ dst,
                                  const int* __restrict__ te, const float* __restrict__ wgt,
                                  const float* __restrict__ fc2b, float* __restrict__ out) {
    int wid = threadIdx.x / 64;
    int lane = threadIdx.x % 64;
    int e = blockIdx.x * 4 + wid;
    if (e >= N_TRAIN) return;
    int id = te[e];
    int a = src[id], b = dst[id];
    const float4* ha = (const float4*)(h + (size_t)a * HIDDEN);
    const float4* hb = (const float4*)(h + (size_t)b * HIDDEN);
    const float4* wf = (const float4*)wgt;
    float acc = 0.f;
    #pragma unroll
    for (int i = 0; i < 2; i++) {
        int idx = lane * 2 + i;
        float4 x = ha[idx], y = hb[idx], z = wf[idx];
        acc += x.x * y.x * z.x + x.y * y.y * z.y + x.z * y.z * z.z + x.w * y.w * z.w;
    }
    #pragma unroll
    for (int o = 32; o > 0; o >>= 1) acc += __shfl_down(acc, o);
    if (lane == 0) out[e] = acc + fc2b[0];
}

// ---------------- launch ----------------

extern "C" void kernel_launch(void* const* d_in, const int* in_sizes, int n_in,
                              void* d_out, int out_size, void* d_ws, size_t ws_size,
                              hipStream_t stream) {
    const float* x    = (const float*)d_in[0];
    const int*   eidx = (const int*)d_in[1];
    const int*   te   = (const int*)d_in[2];
    const float* W1   = (const float*)d_in[3];
    const float* b1   = (const float*)d_in[4];
    const float* W2   = (const float*)d_in[5];
    const float* b2   = (const float*)d_in[6];
    const float* W3   = (const float*)d_in[7];
    const float* b3   = (const float*)d_in[8];
    const float* fc2W = (const float*)d_in[9];
    const float* fc2b = (const float*)d_in[10];
    const int* srcp = eidx;
    const int* dstp = eidx + N_EDGES;

    char* ws = (char*)d_ws;
    size_t used = 0;
    auto alloc = [&](size_t bytes) {
        void* p = ws + used;
        used += (bytes + 255) / 256 * 256;
        return p;
    };
    int*   cnt     = (int*)alloc((size_t)N_NODES * 4);
    int*   off     = (int*)alloc((size_t)(N_NODES + 1) * 4);
    int*   cursor  = (int*)alloc((size_t)N_NODES * 4);
    int*   csr_src = (int*)alloc((size_t)N_EDGES * 4);
    float* dis     = (float*)alloc((size_t)N_NODES * 4);
    unsigned short* Bt1 = (unsigned short*)alloc((size_t)HIDDEN * 3 * IN_DIM * 2);
    unsigned short* Bt2 = (unsigned short*)alloc((size_t)HIDDEN * 3 * HIDDEN * 2);
    unsigned short* Bt3 = (unsigned short*)alloc((size_t)HIDDEN * 3 * HIDDEN * 2);
    unsigned short* GAhi = (unsigned short*)alloc((size_t)M_PAD * HIDDEN * 2);
    unsigned short* GAlo = (unsigned short*)alloc((size_t)M_PAD * HIDDEN * 2);
    float*          F    = (float*)alloc((size_t)M_PAD * HIDDEN * 4);

    if (used > ws_size) return;  // fail cleanly rather than OOB

    hipMemsetAsync(cnt, 0, (size_t)N_NODES * 4, stream);
    hipMemsetAsync(cursor, 0, (size_t)N_NODES * 4, stream);

    count_dst_kernel<<<(N_EDGES + 255) / 256, 256, 0, stream>>>(dstp, cnt);
    dis_kernel<<<(N_NODES + 255) / 256, 256, 0, stream>>>(cnt, dis);
    scan_kernel<<<1, 1024, 0, stream>>>(cnt, off);
    fill_csr_kernel<<<(N_EDGES + 255) / 256, 256, 0, stream>>>(srcp, dstp, off, cursor, csr_src);

    convw_kernel<<<(IN_DIM * HIDDEN + 255) / 256, 256, 0, stream>>>(W1, Bt1, IN_DIM);
    convw_kernel<<<(HIDDEN * HIDDEN + 255) / 256, 256, 0, stream>>>(W2, Bt2, HIDDEN);
    convw_kernel<<<(HIDDEN * HIDDEN + 255) / 256, 256, 0, stream>>>(W3, Bt3, HIDDEN);

    int gemm_blocks = (HIDDEN / 128) * (M_PAD / 128);   // 1564, 1D for XCD swizzle

    // layer 1: split(agg(x)) -> GA;  F = tanh(GA' @ B1' + b1)
    agg_split_kernel<IN_DIM><<<(N_NODES + 7) / 8, 256, 0, stream>>>(x, dis, off, csr_src,
                                                                    GAhi, GAlo);
    gemm_mfma_kernel<<<gemm_blocks, 256, 0, stream>>>(GAhi, GAlo, Bt1, b1, F, N_NODES, IN_DIM);
    // layer 2
    agg_split_kernel<HIDDEN><<<(N_NODES + 1) / 2, 256, 0, stream>>>(F, dis, off, csr_src,
                                                                    GAhi, GAlo);
    gemm_mfma_kernel<<<gemm_blocks, 256, 0, stream>>>(GAhi, GAlo, Bt2, b2, F, N_NODES, HIDDEN);
    // layer 3
    agg_split_kernel<HIDDEN><<<(N_NODES + 1) / 2, 256, 0, stream>>>(F, dis, off, csr_src,
                                                                    GAhi, GAlo);
    gemm_mfma_kernel<<<gemm_blocks, 256, 0, stream>>>(GAhi, GAlo, Bt3, b3, F, N_NODES, HIDDEN);
    // final scoring
    edge_score_kernel<<<(N_TRAIN + 3) / 4, 256, 0, stream>>>(F, srcp, dstp, te, fc2W, fc2b,
                                                             (float*)d_out);
}

// Round 5
// 602.859 us; speedup vs baseline: 2.1933x; 1.4060x over previous
//
#include <hip/hip_runtime.h>
#include <math.h>

#define N_NODES 50000
#define N_EDGES 400000
#define N_TRAIN 50000
#define IN_DIM  128
#define HIDDEN  512
#define M_PAD   50048   // 391 * 128

typedef _Float16 f16;
typedef __attribute__((ext_vector_type(8))) _Float16 f16x8;
typedef __attribute__((ext_vector_type(4))) _Float16 f16x4;
typedef __attribute__((ext_vector_type(4))) float f32x4;

// ---------------- graph preprocessing ----------------

__global__ void count_dst_kernel(const int* __restrict__ dst, int* __restrict__ cnt) {
    int i = blockIdx.x * blockDim.x + threadIdx.x;
    if (i < N_EDGES) atomicAdd(&cnt[dst[i]], 1);
}

__global__ void dis_kernel(const int* __restrict__ cnt, float* __restrict__ dis) {
    int v = blockIdx.x * blockDim.x + threadIdx.x;
    if (v < N_NODES) dis[v] = rsqrtf(1.0f + (float)cnt[v]);  // +1 self-loop
}

__global__ void scan_kernel(const int* __restrict__ cnt, int* __restrict__ off) {
    __shared__ int part[1024];
    const int T = 1024;
    const int chunk = (N_NODES + T - 1) / T;
    int t = threadIdx.x;
    int s = t * chunk, e = min(s + chunk, N_NODES);
    int sum = 0;
    for (int i = s; i < e; i++) sum += cnt[i];
    part[t] = sum;
    __syncthreads();
    for (int o = 1; o < T; o <<= 1) {
        int v = (t >= o) ? part[t - o] : 0;
        __syncthreads();
        part[t] += v;
        __syncthreads();
    }
    int run = part[t] - sum;
    for (int i = s; i < e; i++) { off[i] = run; run += cnt[i]; }
    if (t == T - 1) off[N_NODES] = run;
}

__global__ void fill_csr_kernel(const int* __restrict__ src, const int* __restrict__ dst,
                                const int* __restrict__ off, int* __restrict__ cursor,
                                int* __restrict__ csr_src) {
    int i = blockIdx.x * blockDim.x + threadIdx.x;
    if (i < N_EDGES) {
        int d = dst[i];
        int p = atomicAdd(&cursor[d], 1);
        csr_src[off[d] + p] = src[i];
    }
}

// ------------- weight conversion: W[K][512] -> Bt[512][2K] = [hi | lo] rows -------------
__global__ void convw_kernel(const float* __restrict__ W, f16* __restrict__ Bt, int K) {
    int idx = blockIdx.x * blockDim.x + threadIdx.x;
    if (idx >= K * HIDDEN) return;
    int k = idx / HIDDEN, n = idx % HIDDEN;
    float w = W[(size_t)k * HIDDEN + n];
    f16 hi = (f16)w;
    f16 lo = (f16)(w - (float)hi);
    size_t base = (size_t)n * 2 * K;
    Bt[base + k]     = hi;
    Bt[base + K + k] = lo;
}

// ------------- layer-1 aggregation: f32 x (D=128) -> fp16 (stride 128) -------------
__global__ void agg1_kernel(const float* __restrict__ x, const float* __restrict__ dis,
                            const int* __restrict__ off, const int* __restrict__ csr_src,
                            f16* __restrict__ A) {
    const int TPN = 32;   // 128/4
    int node = blockIdx.x * 8 + threadIdx.x / TPN;
    if (node >= N_NODES) return;
    int t = threadIdx.x % TPN;
    float dv = dis[node];
    float w0 = dv * dv;
    float4 a = ((const float4*)(x + (size_t)node * IN_DIM))[t];
    float4 acc = make_float4(a.x * w0, a.y * w0, a.z * w0, a.w * w0);
    int s0 = off[node], s1 = off[node + 1];
    for (int k = s0; k < s1; k++) {
        int s = csr_src[k];
        float w = dis[s] * dv;
        float4 b = ((const float4*)(x + (size_t)s * IN_DIM))[t];
        acc.x = fmaf(w, b.x, acc.x);
        acc.y = fmaf(w, b.y, acc.y);
        acc.z = fmaf(w, b.z, acc.z);
        acc.w = fmaf(w, b.w, acc.w);
    }
    f16x4 o;
    o.x = (f16)acc.x; o.y = (f16)acc.y; o.z = (f16)acc.z; o.w = (f16)acc.w;
    *(f16x4*)&A[(size_t)node * IN_DIM + t * 4] = o;
}

// ------------- aggregation: fp16 h (512) -> fp16 (stride 512) -------------
__global__ void agg_f16_kernel(const f16* __restrict__ h, const float* __restrict__ dis,
                               const int* __restrict__ off, const int* __restrict__ csr_src,
                               f16* __restrict__ A) {
    const int TPN = 64;   // 512/8
    int node = blockIdx.x * 4 + threadIdx.x / TPN;
    if (node >= N_NODES) return;
    int t = threadIdx.x % TPN;
    float dv = dis[node];
    float w0 = dv * dv;
    f16x8 a = *(const f16x8*)&h[(size_t)node * HIDDEN + t * 8];
    float acc[8];
    #pragma unroll
    for (int j = 0; j < 8; j++) acc[j] = w0 * (float)a[j];
    int s0 = off[node], s1 = off[node + 1];
    for (int k = s0; k < s1; k++) {
        int s = csr_src[k];
        float w = dis[s] * dv;
        f16x8 b = *(const f16x8*)&h[(size_t)s * HIDDEN + t * 8];
        #pragma unroll
        for (int j = 0; j < 8; j++) acc[j] = fmaf(w, (float)b[j], acc[j]);
    }
    f16x8 o;
    #pragma unroll
    for (int j = 0; j < 8; j++) o[j] = (f16)acc[j];
    *(f16x8*)&A[(size_t)node * HIDDEN + t * 8] = o;
}

// ------------- MFMA fp16 GEMM (2-term weight split) + bias + tanh -> fp16 -------------
// C[M][512] = tanh(A @ (B_hi + B_lo) + bias).  Logical K' = 2*Kb, A' = [A | A],
// Bt = [512][2Kb] ([hi | lo]).  Tile 128x128, 4 waves 2x2, BK=64.
// LDS double-buffered (T3 minimum 2-phase): STAGE(t+1) issued before compute(t),
// single __syncthreads per K-step (vmcnt drain lands after compute).
// XOR-swizzle per rule #21: linear LDS dest + inverse-swizzled global src + swizzled read.
__global__ __launch_bounds__(256) void gemm_mfma_kernel(
    const f16* __restrict__ A, const f16* __restrict__ Bt, const float* __restrict__ bias,
    f16* __restrict__ C, int M, int Kb) {
    __shared__ f16 As[2][128 * 64];
    __shared__ f16 Bs[2][128 * 64];
    const int Kp = 2 * Kb;
    int tid = threadIdx.x;
    int lane = tid & 63, w = tid >> 6;
    int wr = w >> 1, wc = w & 1;

    // bijective XCD swizzle (m204)
    int nwg = gridDim.x;
    int q = nwg >> 3, r = nwg & 7;
    int xcd = blockIdx.x & 7, pos = blockIdx.x >> 3;
    int wgid = (xcd < r ? xcd * (q + 1) : r * (q + 1) + (xcd - r) * q) + pos;
    int j0 = (wgid & 3) * 128;
    int i0 = (wgid >> 2) * 128;

    int l15 = lane & 15, l4 = lane >> 4;

    f32x4 acc[4][4];
    #pragma unroll
    for (int m = 0; m < 4; m++)
        #pragma unroll
        for (int n = 0; n < 4; n++)
            acc[m][n] = (f32x4){0.f, 0.f, 0.f, 0.f};

    const int nt = Kp / 64;

    auto stage = [&](int t, int buf) {
        int k0 = t * 64;
        int koff = k0 & (Kb - 1);   // A reused for both hi/lo halves
        #pragma unroll
        for (int i = 0; i < 4; i++) {
            int s = i * 256 + w * 64 + lane;   // 16B-slot index
            int row = s >> 3, c8 = s & 7;
            int c8s = c8 ^ (row & 7);          // inverse-swizzled source column
            const f16* gp = A + (size_t)(i0 + row) * Kb + koff + c8s * 8;
            f16* lp = &As[buf][(i * 256 + w * 64) * 8];   // wave-uniform base
            __builtin_amdgcn_global_load_lds(
                (const __attribute__((address_space(1))) void*)gp,
                (__attribute__((address_space(3))) void*)lp, 16, 0, 0);
        }
        #pragma unroll
        for (int i = 0; i < 4; i++) {
            int s = i * 256 + w * 64 + lane;
            int row = s >> 3, c8 = s & 7;
            int c8s = c8 ^ (row & 7);
            const f16* gp = Bt + (size_t)(j0 + row) * Kp + k0 + c8s * 8;
            f16* lp = &Bs[buf][(i * 256 + w * 64) * 8];
            __builtin_amdgcn_global_load_lds(
                (const __attribute__((address_space(1))) void*)gp,
                (__attribute__((address_space(3))) void*)lp, 16, 0, 0);
        }
    };

    stage(0, 0);
    __syncthreads();   // drain stage(0)

    for (int t = 0; t < nt; t++) {
        int cur = t & 1;
        if (t + 1 < nt) stage(t + 1, cur ^ 1);   // async prefetch under compute

        f16x8 af[4][2], bfr[4][2];
        #pragma unroll
        for (int m = 0; m < 4; m++) {
            int row = wr * 64 + m * 16 + l15;
            #pragma unroll
            for (int kk = 0; kk < 2; kk++) {
                int slot = (kk * 4 + l4) ^ (row & 7);
                af[m][kk] = *(const f16x8*)&As[cur][row * 64 + slot * 8];
            }
        }
        #pragma unroll
        for (int n = 0; n < 4; n++) {
            int row = wc * 64 + n * 16 + l15;
            #pragma unroll
            for (int kk = 0; kk < 2; kk++) {
                int slot = (kk * 4 + l4) ^ (row & 7);
                bfr[n][kk] = *(const f16x8*)&Bs[cur][row * 64 + slot * 8];
            }
        }
        #pragma unroll
        for (int m = 0; m < 4; m++)
            #pragma unroll
            for (int n = 0; n < 4; n++)
                #pragma unroll
                for (int kk = 0; kk < 2; kk++)
                    acc[m][n] = __builtin_amdgcn_mfma_f32_16x16x32_f16(
                        af[m][kk], bfr[n][kk], acc[m][n], 0, 0, 0);

        __syncthreads();   // drains prefetch vmcnt + protects LDS reads
    }

    #pragma unroll
    for (int m = 0; m < 4; m++) {
        #pragma unroll
        for (int n = 0; n < 4; n++) {
            int col = j0 + wc * 64 + n * 16 + l15;
            float bc = bias[col];
            #pragma unroll
            for (int r = 0; r < 4; r++) {
                int row = i0 + wr * 64 + m * 16 + l4 * 4 + r;
                if (row < M)
                    C[(size_t)row * HIDDEN + col] = (f16)tanhf(acc[m][n][r] + bc);
            }
        }
    }
}

// ---------------- final edge scoring (fp16 input) ----------------
__global__ void edge_score_kernel(const f16* __restrict__ h,
                                  const int* __restrict__ src, const int* __restrict__ dst,
                                  const int* __restrict__ te, const float* __restrict__ wgt,
                                  const float* __restrict__ fc2b, float* __restrict__ out) {
    int wid = threadIdx.x / 64;
    int lane = threadIdx.x % 64;
    int e = blockIdx.x * 4 + wid;
    if (e >= N_TRAIN) return;
    int id = te[e];
    int a = src[id], b = dst[id];
    f16x8 ha = *(const f16x8*)&h[(size_t)a * HIDDEN + lane * 8];
    f16x8 hb = *(const f16x8*)&h[(size_t)b * HIDDEN + lane * 8];
    float4 w0 = *(const float4*)&wgt[lane * 8];
    float4 w1 = *(const float4*)&wgt[lane * 8 + 4];
    float acc = 0.f;
    acc += (float)ha[0] * (float)hb[0] * w0.x;
    acc += (float)ha[1] * (float)hb[1] * w0.y;
    acc += (float)ha[2] * (float)hb[2] * w0.z;
    acc += (float)ha[3] * (float)hb[3] * w0.w;
    acc += (float)ha[4] * (float)hb[4] * w1.x;
    acc += (float)ha[5] * (float)hb[5] * w1.y;
    acc += (float)ha[6] * (float)hb[6] * w1.z;
    acc += (float)ha[7] * (float)hb[7] * w1.w;
    #pragma unroll
    for (int o = 32; o > 0; o >>= 1) acc += __shfl_down(acc, o);
    if (lane == 0) out[e] = acc + fc2b[0];
}

// ---------------- launch ----------------

extern "C" void kernel_launch(void* const* d_in, const int* in_sizes, int n_in,
                              void* d_out, int out_size, void* d_ws, size_t ws_size,
                              hipStream_t stream) {
    const float* x    = (const float*)d_in[0];
    const int*   eidx = (const int*)d_in[1];
    const int*   te   = (const int*)d_in[2];
    const float* W1   = (const float*)d_in[3];
    const float* b1   = (const float*)d_in[4];
    const float* W2   = (const float*)d_in[5];
    const float* b2   = (const float*)d_in[6];
    const float* W3   = (const float*)d_in[7];
    const float* b3   = (const float*)d_in[8];
    const float* fc2W = (const float*)d_in[9];
    const float* fc2b = (const float*)d_in[10];
    const int* srcp = eidx;
    const int* dstp = eidx + N_EDGES;

    char* ws = (char*)d_ws;
    size_t used = 0;
    auto alloc = [&](size_t bytes) {
        void* p = ws + used;
        used += (bytes + 255) / 256 * 256;
        return p;
    };
    int*   cnt     = (int*)alloc((size_t)N_NODES * 4);
    int*   off     = (int*)alloc((size_t)(N_NODES + 1) * 4);
    int*   cursor  = (int*)alloc((size_t)N_NODES * 4);
    int*   csr_src = (int*)alloc((size_t)N_EDGES * 4);
    float* dis     = (float*)alloc((size_t)N_NODES * 4);
    f16* Bt1 = (f16*)alloc((size_t)HIDDEN * 2 * IN_DIM * 2);
    f16* Bt2 = (f16*)alloc((size_t)HIDDEN * 2 * HIDDEN * 2);
    f16* Bt3 = (f16*)alloc((size_t)HIDDEN * 2 * HIDDEN * 2);
    f16* GA  = (f16*)alloc((size_t)M_PAD * HIDDEN * 2);   // GEMM A operand
    f16* F   = (f16*)alloc((size_t)M_PAD * HIDDEN * 2);   // layer output

    if (used > ws_size) return;  // fail cleanly rather than OOB

    hipMemsetAsync(cnt, 0, (size_t)N_NODES * 4, stream);
    hipMemsetAsync(cursor, 0, (size_t)N_NODES * 4, stream);

    count_dst_kernel<<<(N_EDGES + 255) / 256, 256, 0, stream>>>(dstp, cnt);
    dis_kernel<<<(N_NODES + 255) / 256, 256, 0, stream>>>(cnt, dis);
    scan_kernel<<<1, 1024, 0, stream>>>(cnt, off);
    fill_csr_kernel<<<(N_EDGES + 255) / 256, 256, 0, stream>>>(srcp, dstp, off, cursor, csr_src);

    convw_kernel<<<(IN_DIM * HIDDEN + 255) / 256, 256, 0, stream>>>(W1, Bt1, IN_DIM);
    convw_kernel<<<(HIDDEN * HIDDEN + 255) / 256, 256, 0, stream>>>(W2, Bt2, HIDDEN);
    convw_kernel<<<(HIDDEN * HIDDEN + 255) / 256, 256, 0, stream>>>(W3, Bt3, HIDDEN);

    int gemm_blocks = (HIDDEN / 128) * (M_PAD / 128);   // 1564, 1D for XCD swizzle

    // layer 1: GA = agg(x);  F = tanh(GA @ W1' + b1)
    agg1_kernel<<<(N_NODES + 7) / 8, 256, 0, stream>>>(x, dis, off, csr_src, GA);
    gemm_mfma_kernel<<<gemm_blocks, 256, 0, stream>>>(GA, Bt1, b1, F, N_NODES, IN_DIM);
    // layer 2
    agg_f16_kernel<<<(N_NODES + 3) / 4, 256, 0, stream>>>(F, dis, off, csr_src, GA);
    gemm_mfma_kernel<<<gemm_blocks, 256, 0, stream>>>(GA, Bt2, b2, F, N_NODES, HIDDEN);
    // layer 3
    agg_f16_kernel<<<(N_NODES + 3) / 4, 256, 0, stream>>>(F, dis, off, csr_src, GA);
    gemm_mfma_kernel<<<gemm_blocks, 256, 0, stream>>>(GA, Bt3, b3, F, N_NODES, HIDDEN);
    // final scoring
    edge_score_kernel<<<(N_TRAIN + 3) / 4, 256, 0, stream>>>(F, srcp, dstp, te, fc2W, fc2b,
                                                             (float*)d_out);
}

// Round 6
// 574.937 us; speedup vs baseline: 2.2999x; 1.0486x over previous
//
#include <hip/hip_runtime.h>
#include <math.h>

#define N_NODES 50000
#define N_EDGES 400000
#define N_TRAIN 50000
#define IN_DIM  128
#define HIDDEN  512
#define M_PAD   50176   // 196 * 256

typedef _Float16 f16;
typedef __attribute__((ext_vector_type(8))) _Float16 f16x8;
typedef __attribute__((ext_vector_type(4))) _Float16 f16x4;
typedef __attribute__((ext_vector_type(4))) float f32x4;

// ---------------- graph preprocessing ----------------

__global__ void count_dst_kernel(const int* __restrict__ dst, int* __restrict__ cnt) {
    int i = blockIdx.x * blockDim.x + threadIdx.x;
    if (i < N_EDGES) atomicAdd(&cnt[dst[i]], 1);
}

__global__ void dis_kernel(const int* __restrict__ cnt, float* __restrict__ dis) {
    int v = blockIdx.x * blockDim.x + threadIdx.x;
    if (v < N_NODES) dis[v] = rsqrtf(1.0f + (float)cnt[v]);  // +1 self-loop
}

__global__ void scan_kernel(const int* __restrict__ cnt, int* __restrict__ off) {
    __shared__ int part[1024];
    const int T = 1024;
    const int chunk = (N_NODES + T - 1) / T;
    int t = threadIdx.x;
    int s = t * chunk, e = min(s + chunk, N_NODES);
    int sum = 0;
    for (int i = s; i < e; i++) sum += cnt[i];
    part[t] = sum;
    __syncthreads();
    for (int o = 1; o < T; o <<= 1) {
        int v = (t >= o) ? part[t - o] : 0;
        __syncthreads();
        part[t] += v;
        __syncthreads();
    }
    int run = part[t] - sum;
    for (int i = s; i < e; i++) { off[i] = run; run += cnt[i]; }
    if (t == T - 1) off[N_NODES] = run;
}

__global__ void fill_csr_kernel(const int* __restrict__ src, const int* __restrict__ dst,
                                const int* __restrict__ off, int* __restrict__ cursor,
                                int* __restrict__ csr_src) {
    int i = blockIdx.x * blockDim.x + threadIdx.x;
    if (i < N_EDGES) {
        int d = dst[i];
        int p = atomicAdd(&cursor[d], 1);
        csr_src[off[d] + p] = src[i];
    }
}

// ------------- weight conversion: W[K][512] -> Bt[512][2K] = [hi | lo] rows -------------
__global__ void convw_kernel(const float* __restrict__ W, f16* __restrict__ Bt, int K) {
    int idx = blockIdx.x * blockDim.x + threadIdx.x;
    if (idx >= K * HIDDEN) return;
    int k = idx / HIDDEN, n = idx % HIDDEN;
    float w = W[(size_t)k * HIDDEN + n];
    f16 hi = (f16)w;
    f16 lo = (f16)(w - (float)hi);
    size_t base = (size_t)n * 2 * K;
    Bt[base + k]     = hi;
    Bt[base + K + k] = lo;
}

// ------------- layer-1 aggregation: f32 x (D=128) -> fp16 (stride 128) -------------
__global__ void agg1_kernel(const float* __restrict__ x, const float* __restrict__ dis,
                            const int* __restrict__ off, const int* __restrict__ csr_src,
                            f16* __restrict__ A) {
    const int TPN = 32;   // 128/4
    int node = blockIdx.x * 8 + threadIdx.x / TPN;
    if (node >= N_NODES) return;
    int t = threadIdx.x % TPN;
    float dv = dis[node];
    float w0 = dv * dv;
    float4 a = ((const float4*)(x + (size_t)node * IN_DIM))[t];
    float4 acc = make_float4(a.x * w0, a.y * w0, a.z * w0, a.w * w0);
    int s0 = off[node], s1 = off[node + 1];
    for (int k = s0; k < s1; k++) {
        int s = csr_src[k];
        float w = dis[s] * dv;
        float4 b = ((const float4*)(x + (size_t)s * IN_DIM))[t];
        acc.x = fmaf(w, b.x, acc.x);
        acc.y = fmaf(w, b.y, acc.y);
        acc.z = fmaf(w, b.z, acc.z);
        acc.w = fmaf(w, b.w, acc.w);
    }
    f16x4 o;
    o.x = (f16)acc.x; o.y = (f16)acc.y; o.z = (f16)acc.z; o.w = (f16)acc.w;
    *(f16x4*)&A[(size_t)node * IN_DIM + t * 4] = o;
}

// ------------- aggregation: fp16 h (512) -> fp16 (stride 512), 2-way unrolled -------------
__global__ void agg_f16_kernel(const f16* __restrict__ h, const float* __restrict__ dis,
                               const int* __restrict__ off, const int* __restrict__ csr_src,
                               f16* __restrict__ A) {
    const int TPN = 64;   // 512/8, one wave per node
    int node = blockIdx.x * 4 + threadIdx.x / TPN;
    if (node >= N_NODES) return;
    int t = threadIdx.x % TPN;
    float dv = dis[node];
    float w0 = dv * dv;
    f16x8 a = *(const f16x8*)&h[(size_t)node * HIDDEN + t * 8];
    float acc0[8], acc1[8];
    #pragma unroll
    for (int j = 0; j < 8; j++) { acc0[j] = w0 * (float)a[j]; acc1[j] = 0.f; }
    int s0 = off[node], s1 = off[node + 1];
    int k = s0;
    for (; k + 2 <= s1; k += 2) {      // two independent gathers in flight
        int sa = csr_src[k], sb = csr_src[k + 1];
        float wa = dis[sa] * dv, wb = dis[sb] * dv;
        f16x8 ba = *(const f16x8*)&h[(size_t)sa * HIDDEN + t * 8];
        f16x8 bb = *(const f16x8*)&h[(size_t)sb * HIDDEN + t * 8];
        #pragma unroll
        for (int j = 0; j < 8; j++) acc0[j] = fmaf(wa, (float)ba[j], acc0[j]);
        #pragma unroll
        for (int j = 0; j < 8; j++) acc1[j] = fmaf(wb, (float)bb[j], acc1[j]);
    }
    if (k < s1) {
        int sa = csr_src[k];
        float wa = dis[sa] * dv;
        f16x8 ba = *(const f16x8*)&h[(size_t)sa * HIDDEN + t * 8];
        #pragma unroll
        for (int j = 0; j < 8; j++) acc0[j] = fmaf(wa, (float)ba[j], acc0[j]);
    }
    f16x8 o;
    #pragma unroll
    for (int j = 0; j < 8; j++) o[j] = (f16)(acc0[j] + acc1[j]);
    *(f16x8*)&A[(size_t)node * HIDDEN + t * 8] = o;
}

// ------- MFMA fp16 GEMM, hi/lo-fused: 256x128 tile, 8 waves, 64 MFMA/wave/barrier -------
// C[M][512] = tanh(A @ (B_hi + B_lo) + bias).  A staged ONCE per physical-K step and
// used against both B_hi and B_lo slices (A' = [A|A] reuse) -> 2x MFMA per barrier,
// 25% less staging. nt = Kb/64 steps. LDS 128KB, 1 block/CU, 2 waves/SIMD.
// XOR-swizzle per rule #21 (linear LDS dest + inverse-swizzled global src + swizzled read).
__global__ __launch_bounds__(512, 2) void gemm_mfma_kernel(
    const f16* __restrict__ A, const f16* __restrict__ Bt, const float* __restrict__ bias,
    f16* __restrict__ C, int M, int Kb) {
    __shared__ f16 As[2][256 * 64];      // 64 KB
    __shared__ f16 Bs[2][2][128 * 64];   // 64 KB  [buf][hi/lo][col][k]
    const int Kp = 2 * Kb;
    int tid = threadIdx.x;
    int lane = tid & 63, wv = tid >> 6;
    int wr = wv >> 2, wc = wv & 3;       // 2 M-halves x 4 N-quarters

    // bijective XCD swizzle (m204); grid 784 = 98*8
    int nwg = gridDim.x;
    int q = nwg >> 3, r = nwg & 7;
    int xcd = blockIdx.x & 7, pos = blockIdx.x >> 3;
    int wgid = (xcd < r ? xcd * (q + 1) : r * (q + 1) + (xcd - r) * q) + pos;
    int j0 = (wgid & 3) * 128;           // 4 col tiles
    int i0 = (wgid >> 2) * 256;          // 196 row tiles

    int l15 = lane & 15, l4 = lane >> 4;

    f32x4 acc[8][2];
    #pragma unroll
    for (int m = 0; m < 8; m++)
        #pragma unroll
        for (int n = 0; n < 2; n++)
            acc[m][n] = (f32x4){0.f, 0.f, 0.f, 0.f};

    const int nt = Kb / 64;

    auto stage = [&](int t, int buf) {
        int k0 = t * 64;
        #pragma unroll
        for (int i = 0; i < 4; i++) {            // A: 256x64 = 2048 slots
            int s = i * 512 + tid;
            int row = s >> 3, c8 = s & 7;
            int c8s = c8 ^ (row & 7);            // inverse-swizzled source column
            const f16* gp = A + (size_t)(i0 + row) * Kb + k0 + c8s * 8;
            f16* lp = &As[buf][(i * 512 + wv * 64) * 8];   // wave-uniform base
            __builtin_amdgcn_global_load_lds(
                (const __attribute__((address_space(1))) void*)gp,
                (__attribute__((address_space(3))) void*)lp, 16, 0, 0);
        }
        #pragma unroll
        for (int v = 0; v < 2; v++) {            // B hi/lo: 128x64 = 1024 slots each
            #pragma unroll
            for (int i = 0; i < 2; i++) {
                int s = i * 512 + tid;
                int row = s >> 3, c8 = s & 7;
                int c8s = c8 ^ (row & 7);
                const f16* gp = Bt + (size_t)(j0 + row) * Kp + v * Kb + k0 + c8s * 8;
                f16* lp = &Bs[buf][v][(i * 512 + wv * 64) * 8];
                __builtin_amdgcn_global_load_lds(
                    (const __attribute__((address_space(1))) void*)gp,
                    (__attribute__((address_space(3))) void*)lp, 16, 0, 0);
            }
        }
    };

    stage(0, 0);
    __syncthreads();   // drain stage(0)

    for (int t = 0; t < nt; t++) {
        int cur = t & 1;
        if (t + 1 < nt) stage(t + 1, cur ^ 1);   // async prefetch under compute

        f16x8 af[8][2], bfr[2][2][2];
        #pragma unroll
        for (int m = 0; m < 8; m++) {
            int row = wr * 128 + m * 16 + l15;
            #pragma unroll
            for (int kk = 0; kk < 2; kk++) {
                int slot = (kk * 4 + l4) ^ (row & 7);
                af[m][kk] = *(const f16x8*)&As[cur][row * 64 + slot * 8];
            }
        }
        #pragma unroll
        for (int n = 0; n < 2; n++) {
            int brow = wc * 32 + n * 16 + l15;
            #pragma unroll
            for (int v = 0; v < 2; v++)
                #pragma unroll
                for (int kk = 0; kk < 2; kk++) {
                    int slot = (kk * 4 + l4) ^ (brow & 7);
                    bfr[n][v][kk] = *(const f16x8*)&Bs[cur][v][brow * 64 + slot * 8];
                }
        }
        #pragma unroll
        for (int m = 0; m < 8; m++)
            #pragma unroll
            for (int n = 0; n < 2; n++)
                #pragma unroll
                for (int v = 0; v < 2; v++)
                    #pragma unroll
                    for (int kk = 0; kk < 2; kk++)
                        acc[m][n] = __builtin_amdgcn_mfma_f32_16x16x32_f16(
                            af[m][kk], bfr[n][v][kk], acc[m][n], 0, 0, 0);

        __syncthreads();   // drains prefetch vmcnt + protects LDS
    }

    #pragma unroll
    for (int m = 0; m < 8; m++) {
        #pragma unroll
        for (int n = 0; n < 2; n++) {
            int col = j0 + wc * 32 + n * 16 + l15;
            float bc = bias[col];
            #pragma unroll
            for (int r = 0; r < 4; r++) {
                int row = i0 + wr * 128 + m * 16 + l4 * 4 + r;
                if (row < M)
                    C[(size_t)row * HIDDEN + col] = (f16)tanhf(acc[m][n][r] + bc);
            }
        }
    }
}

// ---------------- final edge scoring (fp16 input) ----------------
__global__ void edge_score_kernel(const f16* __restrict__ h,
                                  const int* __restrict__ src, const int* __restrict__ dst,
                                  const int* __restrict__ te, const float* __restrict__ wgt,
                                  const float* __restrict__ fc2b, float* __restrict__ out) {
    int wid = threadIdx.x / 64;
    int lane = threadIdx.x % 64;
    int e = blockIdx.x * 4 + wid;
    if (e >= N_TRAIN) return;
    int id = te[e];
    int a = src[id], b = dst[id];
    f16x8 ha = *(const f16x8*)&h[(size_t)a * HIDDEN + lane * 8];
    f16x8 hb = *(const f16x8*)&h[(size_t)b * HIDDEN + lane * 8];
    float4 w0 = *(const float4*)&wgt[lane * 8];
    float4 w1 = *(const float4*)&wgt[lane * 8 + 4];
    float acc = 0.f;
    acc += (float)ha[0] * (float)hb[0] * w0.x;
    acc += (float)ha[1] * (float)hb[1] * w0.y;
    acc += (float)ha[2] * (float)hb[2] * w0.z;
    acc += (float)ha[3] * (float)hb[3] * w0.w;
    acc += (float)ha[4] * (float)hb[4] * w1.x;
    acc += (float)ha[5] * (float)hb[5] * w1.y;
    acc += (float)ha[6] * (float)hb[6] * w1.z;
    acc += (float)ha[7] * (float)hb[7] * w1.w;
    #pragma unroll
    for (int o = 32; o > 0; o >>= 1) acc += __shfl_down(acc, o);
    if (lane == 0) out[e] = acc + fc2b[0];
}

// ---------------- launch ----------------

extern "C" void kernel_launch(void* const* d_in, const int* in_sizes, int n_in,
                              void* d_out, int out_size, void* d_ws, size_t ws_size,
                              hipStream_t stream) {
    const float* x    = (const float*)d_in[0];
    const int*   eidx = (const int*)d_in[1];
    const int*   te   = (const int*)d_in[2];
    const float* W1   = (const float*)d_in[3];
    const float* b1   = (const float*)d_in[4];
    const float* W2   = (const float*)d_in[5];
    const float* b2   = (const float*)d_in[6];
    const float* W3   = (const float*)d_in[7];
    const float* b3   = (const float*)d_in[8];
    const float* fc2W = (const float*)d_in[9];
    const float* fc2b = (const float*)d_in[10];
    const int* srcp = eidx;
    const int* dstp = eidx + N_EDGES;

    char* ws = (char*)d_ws;
    size_t used = 0;
    auto alloc = [&](size_t bytes) {
        void* p = ws + used;
        used += (bytes + 255) / 256 * 256;
        return p;
    };
    int*   cnt     = (int*)alloc((size_t)N_NODES * 4);
    int*   off     = (int*)alloc((size_t)(N_NODES + 1) * 4);
    int*   cursor  = (int*)alloc((size_t)N_NODES * 4);
    int*   csr_src = (int*)alloc((size_t)N_EDGES * 4);
    float* dis     = (float*)alloc((size_t)N_NODES * 4);
    f16* Bt1 = (f16*)alloc((size_t)HIDDEN * 2 * IN_DIM * 2);
    f16* Bt2 = (f16*)alloc((size_t)HIDDEN * 2 * HIDDEN * 2);
    f16* Bt3 = (f16*)alloc((size_t)HIDDEN * 2 * HIDDEN * 2);
    f16* GA  = (f16*)alloc((size_t)M_PAD * HIDDEN * 2);   // GEMM A operand
    f16* F   = (f16*)alloc((size_t)M_PAD * HIDDEN * 2);   // layer output

    if (used > ws_size) return;  // fail cleanly rather than OOB

    hipMemsetAsync(cnt, 0, (size_t)N_NODES * 4, stream);
    hipMemsetAsync(cursor, 0, (size_t)N_NODES * 4, stream);

    count_dst_kernel<<<(N_EDGES + 255) / 256, 256, 0, stream>>>(dstp, cnt);
    dis_kernel<<<(N_NODES + 255) / 256, 256, 0, stream>>>(cnt, dis);
    scan_kernel<<<1, 1024, 0, stream>>>(cnt, off);
    fill_csr_kernel<<<(N_EDGES + 255) / 256, 256, 0, stream>>>(srcp, dstp, off, cursor, csr_src);

    convw_kernel<<<(IN_DIM * HIDDEN + 255) / 256, 256, 0, stream>>>(W1, Bt1, IN_DIM);
    convw_kernel<<<(HIDDEN * HIDDEN + 255) / 256, 256, 0, stream>>>(W2, Bt2, HIDDEN);
    convw_kernel<<<(HIDDEN * HIDDEN + 255) / 256, 256, 0, stream>>>(W3, Bt3, HIDDEN);

    int gemm_blocks = (HIDDEN / 128) * (M_PAD / 256);   // 784 = 98*8, 1D for XCD swizzle

    // layer 1: GA = agg(x);  F = tanh(GA @ W1' + b1)
    agg1_kernel<<<(N_NODES + 7) / 8, 256, 0, stream>>>(x, dis, off, csr_src, GA);
    gemm_mfma_kernel<<<gemm_blocks, 512, 0, stream>>>(GA, Bt1, b1, F, N_NODES, IN_DIM);
    // layer 2
    agg_f16_kernel<<<(N_NODES + 3) / 4, 256, 0, stream>>>(F, dis, off, csr_src, GA);
    gemm_mfma_kernel<<<gemm_blocks, 512, 0, stream>>>(GA, Bt2, b2, F, N_NODES, HIDDEN);
    // layer 3
    agg_f16_kernel<<<(N_NODES + 3) / 4, 256, 0, stream>>>(F, dis, off, csr_src, GA);
    gemm_mfma_kernel<<<gemm_blocks, 512, 0, stream>>>(GA, Bt3, b3, F, N_NODES, HIDDEN);
    // final scoring
    edge_score_kernel<<<(N_TRAIN + 3) / 4, 256, 0, stream>>>(F, srcp, dstp, te, fc2W, fc2b,
                                                             (float*)d_out);
}